// Round 9
// baseline (163.520 us; speedup 1.0000x reference)
//
#include <hip/hip_runtime.h>
#include <stdint.h>

// LinearBin: out = x @ sign(W)^T + bias   (B=131072, IN=OUT=512, fp32)
// v9: phase-diversity version of v8. BM 64->32 (LDS 32KB), wave tile 32x128
//     (fn=4), 4 waves/block, 4 blocks/CU resident so per-CU HBM read/write
//     bursts overlap other blocks' L2-only K-loops. Same proven pieces:
//     carry-free XOR LDS layout, fragment-major B, bias folded into acc,
//     ONE barrier, 1-deep register rotation, direct epilogue stores.

#define BATCH   131072
#define IN_F    512
#define OUT_F   512
#define BM      32
#define NKT     32            // K-steps of 16

using f32x4  = __attribute__((ext_vector_type(4))) float;
using f32x16 = __attribute__((ext_vector_type(16))) float;
using short8 = __attribute__((ext_vector_type(8))) short;
using usv8   = __attribute__((ext_vector_type(8))) unsigned short;
using u32    = uint32_t;

// ---------------- prep: binarize W into 32x32x16-fragment-major bf16 --------
// (verified r6/r8)  wf[((kt*16+nf)*64+l)*8+j] = sign(W[nf*32+(l&31)][kt*16+(l>>5)*8+j])
__global__ void prep_w(const float* __restrict__ W, unsigned short* __restrict__ wf) {
    int t = blockIdx.x * blockDim.x + threadIdx.x; // 32768 threads
    int l  = t & 63;
    int nf = (t >> 6) & 15;
    int kt = t >> 10;
    int n = nf * 32 + (l & 31);
    int k = kt * 16 + ((l >> 5) << 3);
    const float* src = W + (size_t)n * IN_F + k;
    f32x4 w0 = *(const f32x4*)(src);
    f32x4 w1 = *(const f32x4*)(src + 4);
    usv8 o;
#pragma unroll
    for (int j = 0; j < 4; ++j) {
        o[j]     = (w0[j] >= 0.0f) ? 0x3F80u : 0xBF80u; // +1.0 / -1.0 bf16
        o[j + 4] = (w1[j] >= 0.0f) ? 0x3F80u : 0xBF80u;
    }
    *(usv8*)(wf + (size_t)t * 8) = o;
}

// ---------------- GEMM: one barrier, then barrier-free K-loop ----------------
__global__ __launch_bounds__(256, 4) void gemm_bin(
    const float* __restrict__ X, const unsigned short* __restrict__ WF,
    const float* __restrict__ bias, float* __restrict__ out) {

    // 32 rows x 512 bf16, row stride 1KB, 16B slots XOR-swizzled by (row&7).
    __shared__ __align__(16) unsigned short lds[BM * IN_F]; // 32KB

    const int tid  = threadIdx.x;
    const int lane = tid & 63;
    const int wv   = tid >> 6;              // 0..3 -> 128-col strip
    const int m0   = blockIdx.x * BM;       // grid = 4096

    // ---- stage whole x-strip as bf16 (once) ----
    {
        const int r  = tid >> 3;            // 0..31
        const int sg = tid & 7;
        const float* xr = X + (size_t)(m0 + r) * IN_F;
        char* lrow = (char*)lds + r * 1024;
        const int swz = (r & 7) << 4;
#pragma unroll
        for (int p = 0; p < 8; ++p) {
            const int f0 = sg * 8 + p * 64;
            f32x4 a = *(const f32x4*)(xr + f0);
            f32x4 b = *(const f32x4*)(xr + f0 + 4);
            u32 w0, w1, w2, w3;
            asm("v_cvt_pk_bf16_f32 %0, %1, %2" : "=v"(w0) : "v"(a[0]), "v"(a[1]));
            asm("v_cvt_pk_bf16_f32 %0, %1, %2" : "=v"(w1) : "v"(a[2]), "v"(a[3]));
            asm("v_cvt_pk_bf16_f32 %0, %1, %2" : "=v"(w2) : "v"(b[0]), "v"(b[1]));
            asm("v_cvt_pk_bf16_f32 %0, %1, %2" : "=v"(w3) : "v"(b[2]), "v"(b[3]));
            union { u32 w[4]; usv8 v; } pk;
            pk.w[0] = w0; pk.w[1] = w1; pk.w[2] = w2; pk.w[3] = w3;
            *(usv8*)(lrow + ((sg * 16 + p * 128) ^ swz)) = pk.v;
        }
    }

    // ---- bias -> accumulator init (C/D col = lane&31; bias is col-only) ----
    f32x16 acc[4];
#pragma unroll
    for (int fn = 0; fn < 4; ++fn) {
        const float bv = bias[wv * 128 + fn * 32 + (lane & 31)];
#pragma unroll
        for (int r = 0; r < 16; ++r) acc[fn][r] = bv;
    }
    __syncthreads();   // the ONLY barrier

    // ---- A/B fragment geometry ----
    // A: lane l -> row (l&31), floats kt*16 + (l>>5)*8.
    //    slot byte = (kt*32 + ((l>>5)<<4)) ^ ((row&7)<<4)  -- carry-free XOR.
    const int arow  = (lane & 31) * 1024;
    const int ak4   = (lane >> 5) << 4;
    const int aswz  = (lane & 7) << 4;
    const char* lptr = (const char*)lds;
    // B: fragment-major; short8 index = (kt*16 + nf)*64 + lane, nf = wv*4+fn
    const short8* wb = (const short8*)(WF) + ((size_t)(wv * 4) * 64 + lane);

#define LDA(dst, kt_)                                                          \
    {                                                                          \
        const int koff_ = ((kt_) * 32 + ak4) ^ aswz;                           \
        dst = *(const short8*)(lptr + arow + koff_);                           \
    }
#define LDB(dst, kt_)                                                          \
    {                                                                          \
        _Pragma("unroll")                                                      \
        for (int fn = 0; fn < 4; ++fn)                                         \
            dst[fn] = wb[(kt_) * 1024 + fn * 64];                              \
    }

    short8 af[2], bf[2][4];
    LDA(af[0], 0);
    LDB(bf[0], 0);

#pragma unroll
    for (int kt = 0; kt < NKT; ++kt) {
        const int cur = kt & 1;
        if (kt < NKT - 1) {
            LDB(bf[cur ^ 1], kt + 1);
            LDA(af[cur ^ 1], kt + 1);
        }
#pragma unroll
        for (int fn = 0; fn < 4; ++fn)
            acc[fn] = __builtin_amdgcn_mfma_f32_32x32x16_bf16(
                af[cur], bf[cur][fn], acc[fn], 0, 0, 0);
    }
#undef LDA
#undef LDB

    // ---- epilogue: direct stores (bias already in acc) ----
    // C/D: col = lane&31, row = (r&3) + 8*(r>>2) + 4*(lane>>5)
    const int c     = lane & 31;
    const int rbase = (lane >> 5) << 2;
#pragma unroll
    for (int fn = 0; fn < 4; ++fn)
#pragma unroll
        for (int r = 0; r < 16; ++r) {
            const int row = (r & 3) + 8 * (r >> 2) + rbase;
            out[(size_t)(m0 + row) * OUT_F + wv * 128 + fn * 32 + c] =
                acc[fn][r];
        }
}

extern "C" void kernel_launch(void* const* d_in, const int* in_sizes, int n_in,
                              void* d_out, int out_size, void* d_ws, size_t ws_size,
                              hipStream_t stream) {
    const float* X    = (const float*)d_in[0];
    const float* W    = (const float*)d_in[1];
    const float* bias = (const float*)d_in[2];
    float* o          = (float*)d_out;
    unsigned short* wf = (unsigned short*)d_ws; // 512KB fragment-major binarized W

    hipLaunchKernelGGL(prep_w, dim3(128), dim3(256), 0, stream, W, wf);
    hipLaunchKernelGGL(gemm_bin, dim3(BATCH / BM), dim3(256), 0, stream,
                       X, wf, bias, o);
}